// Round 5
// baseline (524.950 us; speedup 1.0000x reference)
//
#include <hip/hip_runtime.h>
#include <stdint.h>
#include <stddef.h>

#define BATCH 16
#define SEQ 2048
#define HDIM 256
#define SCHUNK 32
#define TTILE 128
#define NCHUNK 64            // SEQ / SCHUNK
#define NPAIR 32             // chunk pairs
#define TILE_U16 8192        // 16 KB tile (32 x 256 halves)
#define NTILES 1024          // BATCH * NCHUNK
#define KSTRIDE 260          // prepass fp32 staging row stride (bank stride 4)
#define PSTRIDE 40           // P row stride in u16

typedef float f32x4 __attribute__((ext_vector_type(4)));
typedef float f32x16 __attribute__((ext_vector_type(16)));
typedef _Float16 f16x8 __attribute__((ext_vector_type(8)));
typedef __bf16 bf16x8 __attribute__((ext_vector_type(8)));
typedef unsigned short u16;
typedef u16 u16x4 __attribute__((ext_vector_type(4)));
typedef u16 u16x8 __attribute__((ext_vector_type(8)));
typedef unsigned int u32;
typedef const __attribute__((address_space(1))) u32* gp1_t;
typedef __attribute__((address_space(3))) u32* lp3_t;

static __device__ __forceinline__ u16 f2bf(float f) {
  union { float f; unsigned int u; } v; v.f = f;
  unsigned int u = v.u;
  unsigned int r = u + 0x7FFFu + ((u >> 16) & 1u);  // RNE
  return (u16)(r >> 16);
}

// ============================================================================
// Pre-pass: enc [S,B,2H] fp32 -> fragment-ordered tiles per (b,chunk):
//   KH (fp16):  [kb 0..15][lane(m,g)][j] = K[s=m][h=kb*16+g*8+j]   (QK A-op)
//   VT (bf16):  [ht*2+ka][lane][j]      = K[s=ka*16+g*8+j][h=ht*32+m] (PV B-op)
// ============================================================================
__global__ __launch_bounds__(256, 4)
void prepass_kernel(const float* __restrict__ e,
                    u16* __restrict__ KH, u16* __restrict__ VT) {
  __shared__ float Ks[SCHUNK * KSTRIDE];
  const int tid = threadIdx.x;
  const int b  = blockIdx.x >> 6;
  const int ck = blockIdx.x & 63;
  const size_t tile = (size_t)blockIdx.x * TILE_U16;

  {
    int row = tid >> 3;
    int c8  = tid & 7;
    const float* src = e + ((size_t)(ck * SCHUNK + row) * BATCH + b) * (2 * HDIM);
#pragma unroll
    for (int u = 0; u < 8; ++u) {
      int col = c8 * 4 + 32 * u;
      float4 xa = *(const float4*)(src + col);
      float4 xb = *(const float4*)(src + col + HDIM);
      float4 s; s.x = xa.x + xb.x; s.y = xa.y + xb.y; s.z = xa.z + xb.z; s.w = xa.w + xb.w;
      *(float4*)&Ks[row * KSTRIDE + col] = s;
    }
  }
  __syncthreads();

  const int lane = tid & 63;
  const int w = tid >> 6;
  const int m = lane & 31;
  const int g = lane >> 5;

#pragma unroll
  for (int i = 0; i < 4; ++i) {
    int kb = w * 4 + i;
    const float* rp = &Ks[m * KSTRIDE + kb * 16 + g * 8];
    u16x8 hi;
#pragma unroll
    for (int j = 0; j < 8; ++j)
      hi[j] = __builtin_bit_cast(u16, (_Float16)rp[j]);
    *(u16x8*)&KH[tile + (size_t)(kb * 64 + lane) * 8] = hi;
  }

#pragma unroll
  for (int i = 0; i < 4; ++i) {
    int fr = w * 4 + i;
    int ht = fr >> 1, ka = fr & 1;
    u16x8 v;
#pragma unroll
    for (int j = 0; j < 8; ++j)
      v[j] = f2bf(Ks[(ka * 16 + g * 8 + j) * KSTRIDE + ht * 32 + m]);
    *(u16x8*)&VT[tile + (size_t)(fr * 64 + lane) * 8] = v;
  }
}

// ============================================================================
// Main: 512 threads (8 waves, 2/SIMD), source-split (grp 0 even chunks,
// grp 1 odd), 32 targets/wave via 32x32x16. Split-phase pipeline:
// iter j = exp/P(j-1) then interleaved QK(j) + PV(j-1) (one long
// independent MFMA+ds_read stream per wave). VT staged one iter behind KH.
// ============================================================================
__global__ __launch_bounds__(512, 2)
void attn_main_kernel(const u16* __restrict__ KH, const u16* __restrict__ VT,
                      const float* __restrict__ dq,  // [T, B, H]
                      float* __restrict__ out) {     // [T, B, H]
  __shared__ alignas(16) u16 KHs[4][TILE_U16];    // 64 KB
  __shared__ alignas(16) u16 VTs[4][TILE_U16];    // 64 KB
  __shared__ alignas(16) u16 Pb[8][32 * PSTRIDE]; // 20 KB

  const int tid  = threadIdx.x;
  const int lane = tid & 63;
  const int wv   = tid >> 6;        // 0..7
  const int wq   = wv & 3;          // target-group 0..3
  const int grp  = wv >> 2;         // 0 = even chunks, 1 = odd chunks
  const int m    = lane & 31;
  const int g    = lane >> 5;

  const int b  = blockIdx.x >> 4;
  const int t0 = (blockIdx.x & 15) * TTILE;

  // ---- Q fragments fp16 (B-operand: B[k=g*8+j][n=m]) ----
  const int tq = t0 + wq * 32 + m;
  const float* qp = dq + ((size_t)tq * BATCH + b) * HDIM;
  f16x8 qh[16];
#pragma unroll
  for (int kb = 0; kb < 16; ++kb) {
    int h = kb * 16 + g * 8;
    float4 f0 = *(const float4*)(qp + h);
    float4 f1 = *(const float4*)(qp + h + 4);
    float xs[8] = {f0.x, f0.y, f0.z, f0.w, f1.x, f1.y, f1.z, f1.w};
    u16x8 hb;
#pragma unroll
    for (int j = 0; j < 8; ++j)
      hb[j] = __builtin_bit_cast(u16, (_Float16)xs[j]);
    qh[kb] = __builtin_bit_cast(f16x8, hb);
  }

  f32x16 ctx[8];
#pragma unroll
  for (int ht = 0; ht < 8; ++ht) ctx[ht] = (f32x16)(0.0f);
  float dsum = 0.0f;
  f32x16 accA, accB;                 // QK partial scores, live across iters
  bf16x8 pa0, pa1;                   // P A-fragments

  const size_t bbase = (size_t)b * NCHUNK;

  // ---- prologue: stage KH chunks 0,1 (8 waves x 4 subs) ----
  {
    int c = wv >> 2;                 // 0 or 1
    int sb4 = (wv & 3) * 4;
    size_t tb = (bbase + c) * TILE_U16;
    u16* dst = &KHs[c][0];
#pragma unroll
    for (int i = 0; i < 4; ++i) {
      int sub = sb4 + i;
      __builtin_amdgcn_global_load_lds(
          (gp1_t)(const void*)&KH[tb + (size_t)sub * 512 + lane * 8],
          (lp3_t)(void*)&dst[sub * 512], 16, 0, 0);
    }
  }

  // staging roles for the main loop
  const int role = wv >> 1;          // 0,1: KH(pair j+1); 2,3: VT(pair j)
  const int par  = role & 1;
  const int sb   = (wv & 1) * 8;

  auto stage_iter = [&](int j) {
    if (role < 2) {
      int pair = j + 1;
      if (pair < NPAIR) {
        int c = 2 * pair + par;
        size_t tb = (bbase + c) * TILE_U16;
        u16* dst = &KHs[c & 3][0];
#pragma unroll
        for (int i = 0; i < 8; ++i) {
          int sub = sb + i;
          __builtin_amdgcn_global_load_lds(
              (gp1_t)(const void*)&KH[tb + (size_t)sub * 512 + lane * 8],
              (lp3_t)(void*)&dst[sub * 512], 16, 0, 0);
        }
      }
    } else {
      int c = 2 * j + par;
      size_t tb = (bbase + c) * TILE_U16;
      u16* dst = &VTs[c & 3][0];
#pragma unroll
      for (int i = 0; i < 8; ++i) {
        int sub = sb + i;
        __builtin_amdgcn_global_load_lds(
            (gp1_t)(const void*)&VT[tb + (size_t)sub * 512 + lane * 8],
            (lp3_t)(void*)&dst[sub * 512], 16, 0, 0);
      }
    }
  };

  auto expP = [&]() {   // consume accA/accB -> Pb -> pa0/pa1, accumulate dsum
    u16 pbits[16];
    float l0 = 0.f, l1 = 0.f;
#pragma unroll
    for (int r = 0; r < 16; r += 2) {
      float pf0 = __expf(accA[r] + accB[r] - 128.0f);
      float pf1 = __expf(accA[r + 1] + accB[r + 1] - 128.0f);
      l0 += pf0; l1 += pf1;
      pbits[r] = f2bf(pf0); pbits[r + 1] = f2bf(pf1);
    }
    dsum += l0 + l1;
#pragma unroll
    for (int rr = 0; rr < 4; ++rr) {
      u16x4 w4 = {pbits[4 * rr], pbits[4 * rr + 1], pbits[4 * rr + 2], pbits[4 * rr + 3]};
      *(u16x4*)&Pb[wv][m * PSTRIDE + rr * 8 + g * 4] = w4;   // s = 8rr+4g+0..3
    }
    pa0 = __builtin_bit_cast(bf16x8, *(const u16x8*)&Pb[wv][m * PSTRIDE + g * 8]);
    pa1 = __builtin_bit_cast(bf16x8, *(const u16x8*)&Pb[wv][m * PSTRIDE + 16 + g * 8]);
  };

  // ---- iter 0: stage KH pair1 + VT pair0; QK(chunk grp) only ----
  __syncthreads();
  stage_iter(0);
  {
    const u16* KHb = &KHs[grp][0];
    f32x16 nA = (f32x16)(0.0f), nB = (f32x16)(0.0f);
#pragma unroll
    for (int i = 0; i < 8; ++i) {
      f16x8 k0 = __builtin_bit_cast(f16x8, *(const u16x8*)&KHb[(2 * i) * 512 + lane * 8]);
      f16x8 k1 = __builtin_bit_cast(f16x8, *(const u16x8*)&KHb[(2 * i + 1) * 512 + lane * 8]);
      nA = __builtin_amdgcn_mfma_f32_32x32x16_f16(k0, qh[2 * i], nA, 0, 0, 0);
      nB = __builtin_amdgcn_mfma_f32_32x32x16_f16(k1, qh[2 * i + 1], nB, 0, 0, 0);
    }
    accA = nA; accB = nB;
  }

  // ---- main loop ----
#pragma unroll 2
  for (int j = 1; j < NPAIR; ++j) {
    __syncthreads();            // KH pair j & VT pair j-1 staged; old bufs free
    stage_iter(j);
    expP();                     // P(j-1) from accA/accB

    const int ck_q = 2 * j + grp;
    const int ck_v = ck_q - 2;
    const u16* KHb = &KHs[ck_q & 3][0];
    const u16* VTb = &VTs[ck_v & 3][0];
    f32x16 nA = (f32x16)(0.0f), nB = (f32x16)(0.0f);
#pragma unroll
    for (int i = 0; i < 8; ++i) {
      f16x8 k0 = __builtin_bit_cast(f16x8, *(const u16x8*)&KHb[(2 * i) * 512 + lane * 8]);
      f16x8 k1 = __builtin_bit_cast(f16x8, *(const u16x8*)&KHb[(2 * i + 1) * 512 + lane * 8]);
      bf16x8 v0 = __builtin_bit_cast(bf16x8, *(const u16x8*)&VTb[(2 * i) * 512 + lane * 8]);
      bf16x8 v1 = __builtin_bit_cast(bf16x8, *(const u16x8*)&VTb[(2 * i + 1) * 512 + lane * 8]);
      nA = __builtin_amdgcn_mfma_f32_32x32x16_f16(k0, qh[2 * i], nA, 0, 0, 0);
      ctx[i] = __builtin_amdgcn_mfma_f32_32x32x16_bf16(pa0, v0, ctx[i], 0, 0, 0);
      nB = __builtin_amdgcn_mfma_f32_32x32x16_f16(k1, qh[2 * i + 1], nB, 0, 0, 0);
      ctx[i] = __builtin_amdgcn_mfma_f32_32x32x16_bf16(pa1, v1, ctx[i], 0, 0, 0);
    }
    accA = nA; accB = nB;
  }

  // ---- epilogue: last PV (pair 31; VT staged during iter 31) ----
  __syncthreads();
  expP();
  {
    const int ck_v = 2 * (NPAIR - 1) + grp;
    const u16* VTb = &VTs[ck_v & 3][0];
#pragma unroll
    for (int i = 0; i < 8; ++i) {
      bf16x8 v0 = __builtin_bit_cast(bf16x8, *(const u16x8*)&VTb[(2 * i) * 512 + lane * 8]);
      bf16x8 v1 = __builtin_bit_cast(bf16x8, *(const u16x8*)&VTb[(2 * i + 1) * 512 + lane * 8]);
      ctx[i] = __builtin_amdgcn_mfma_f32_32x32x16_bf16(pa0, v0, ctx[i], 0, 0, 0);
      ctx[i] = __builtin_amdgcn_mfma_f32_32x32x16_bf16(pa1, v1, ctx[i], 0, 0, 0);
    }
  }

  // ---- combine the two source-halves (exact: same exp offset) ----
  dsum += __shfl_xor(dsum, 32, 64);   // per-lane: partial denom for t = m
  __syncthreads();                    // all K-loop LDS reads done; bufs reusable

  float* exch = (wq < 2) ? (float*)&KHs[wq * 2][0] : (float*)&VTs[(wq - 2) * 2][0];

  if (grp == 1) {
#pragma unroll
    for (int r4 = 0; r4 < 4; ++r4)
#pragma unroll
      for (int ht = 0; ht < 8; ++ht) {
        f32x4 v = {ctx[ht][r4 * 4], ctx[ht][r4 * 4 + 1],
                   ctx[ht][r4 * 4 + 2], ctx[ht][r4 * 4 + 3]};
        *(f32x4*)&exch[r4 * 2048 + ht * 256 + lane * 4] = v;
      }
    ((float*)&Pb[wv][0])[lane] = dsum;
  }
  __syncthreads();

  if (grp == 0) {
    float dB = ((const float*)&Pb[wv + 4][0])[lane];
    float inv = 1.0f / (dsum + dB);
#pragma unroll
    for (int r4 = 0; r4 < 4; ++r4)
#pragma unroll
      for (int ht = 0; ht < 8; ++ht) {
        f32x4 v = *(const f32x4*)&exch[r4 * 2048 + ht * 256 + lane * 4];
        ctx[ht][r4 * 4]     += v[0];
        ctx[ht][r4 * 4 + 1] += v[1];
        ctx[ht][r4 * 4 + 2] += v[2];
        ctx[ht][r4 * 4 + 3] += v[3];
      }
#pragma unroll
    for (int r = 0; r < 16; ++r) {
      int tl = (r & 3) + 8 * (r >> 2) + 4 * g;
      float rinv = __shfl(inv, tl, 64);
      int t = t0 + wq * 32 + tl;
      float* op = out + ((size_t)t * BATCH + b) * HDIM + m;
#pragma unroll
      for (int ht = 0; ht < 8; ++ht)
        op[ht * 32] = ctx[ht][r] * rinv;
    }
  }
}

extern "C" void kernel_launch(void* const* d_in, const int* in_sizes, int n_in,
                              void* d_out, int out_size, void* d_ws, size_t ws_size,
                              hipStream_t stream) {
  const float* e  = (const float*)d_in[0];  // out_e [2048, 16, 512]
  const float* dq = (const float*)d_in[1];  // out_d [2048, 16, 256]
  float* out = (float*)d_out;               // [2048, 16, 256]
  u16* KH = (u16*)d_ws;                                 // fp16 bits, 16 MB
  u16* VT = KH + (size_t)NTILES * TILE_U16;             // bf16 bits, 16 MB
  prepass_kernel<<<dim3(NTILES), dim3(256), 0, stream>>>(e, KH, VT);
  attn_main_kernel<<<dim3(BATCH * (SEQ / TTILE)), dim3(512), 0, stream>>>(
      KH, VT, dq, out);
}

// Round 6
// 204.824 us; speedup vs baseline: 2.5629x; 2.5629x over previous
//
#include <hip/hip_runtime.h>
#include <stdint.h>
#include <stddef.h>

#define BATCH 16
#define SEQ 2048
#define HDIM 256
#define SCHUNK 32
#define TTILE 128
#define NCHUNK 64            // SEQ / SCHUNK
#define TILE_U16 8192        // 16 KB tile (32 x 256 halves)
#define NTILES 1024          // BATCH * NCHUNK
#define KSTRIDE 260          // prepass fp32 staging row stride (bank stride 4)

typedef float f32x4 __attribute__((ext_vector_type(4)));
typedef float f32x16 __attribute__((ext_vector_type(16)));
typedef _Float16 f16x8 __attribute__((ext_vector_type(8)));
typedef __bf16 bf16x8 __attribute__((ext_vector_type(8)));
typedef unsigned short u16;
typedef u16 u16x8 __attribute__((ext_vector_type(8)));
typedef unsigned int u32;
typedef u32 u32x4 __attribute__((ext_vector_type(4)));
typedef const __attribute__((address_space(1))) u32* gp1_t;
typedef __attribute__((address_space(3))) u32* lp3_t;

static __device__ __forceinline__ u16 f2bf(float f) {
  union { float f; unsigned int u; } v; v.f = f;
  unsigned int u = v.u;
  unsigned int r = u + 0x7FFFu + ((u >> 16) & 1u);  // RNE
  return (u16)(r >> 16);
}

// ============================================================================
// Pre-pass: enc [S,B,2H] fp32 -> fragment-ordered tiles per (b,chunk):
//   KH (fp16):  [kb 0..15][lane(m,g)][j] = K[s=m][h=kb*16+g*8+j]   (QK A-op)
//   VT (bf16):  [ht*2+ka][lane][j]      = K[s=ka*16+g*8+j][h=ht*32+m] (PV B-op)
// ============================================================================
__global__ __launch_bounds__(256, 4)
void prepass_kernel(const float* __restrict__ e,
                    u16* __restrict__ KH, u16* __restrict__ VT) {
  __shared__ float Ks[SCHUNK * KSTRIDE];
  const int tid = threadIdx.x;
  const int b  = blockIdx.x >> 6;
  const int ck = blockIdx.x & 63;
  const size_t tile = (size_t)blockIdx.x * TILE_U16;

  {
    int row = tid >> 3;
    int c8  = tid & 7;
    const float* src = e + ((size_t)(ck * SCHUNK + row) * BATCH + b) * (2 * HDIM);
#pragma unroll
    for (int u = 0; u < 8; ++u) {
      int col = c8 * 4 + 32 * u;
      float4 xa = *(const float4*)(src + col);
      float4 xb = *(const float4*)(src + col + HDIM);
      float4 s; s.x = xa.x + xb.x; s.y = xa.y + xb.y; s.z = xa.z + xb.z; s.w = xa.w + xb.w;
      *(float4*)&Ks[row * KSTRIDE + col] = s;
    }
  }
  __syncthreads();

  const int lane = tid & 63;
  const int w = tid >> 6;
  const int m = lane & 31;
  const int g = lane >> 5;

#pragma unroll
  for (int i = 0; i < 4; ++i) {
    int kb = w * 4 + i;
    const float* rp = &Ks[m * KSTRIDE + kb * 16 + g * 8];
    u16x8 hi;
#pragma unroll
    for (int j = 0; j < 8; ++j)
      hi[j] = __builtin_bit_cast(u16, (_Float16)rp[j]);
    *(u16x8*)&KH[tile + (size_t)(kb * 64 + lane) * 8] = hi;
  }

#pragma unroll
  for (int i = 0; i < 4; ++i) {
    int fr = w * 4 + i;
    int ht = fr >> 1, ka = fr & 1;
    u16x8 v;
#pragma unroll
    for (int j = 0; j < 8; ++j)
      v[j] = f2bf(Ks[(ka * 16 + g * 8 + j) * KSTRIDE + ht * 32 + m]);
    *(u16x8*)&VT[tile + (size_t)(fr * 64 + lane) * 8] = v;
  }
}

// ============================================================================
// Main: 512 threads (8 waves, 2/SIMD), source-split (grp 0 even chunks,
// grp 1 odd), 32 targets/wave via 32x32x16. Round-4 sequential per-chunk
// QK -> exp -> PV, but P transposed C-layout -> A-layout IN REGISTERS
// (8x shfl_xor(32) + selects) instead of through LDS.
// ============================================================================
__global__ __launch_bounds__(512, 2)
void attn_main_kernel(const u16* __restrict__ KH, const u16* __restrict__ VT,
                      const float* __restrict__ dq,  // [T, B, H]
                      float* __restrict__ out) {     // [T, B, H]
  __shared__ alignas(16) u16 KHs[4][TILE_U16];   // 64 KB
  __shared__ alignas(16) u16 VTs[4][TILE_U16];   // 64 KB
  __shared__ alignas(16) float Ds[4][64];        // 1 KB (grp1 partial denoms)

  const int tid  = threadIdx.x;
  const int lane = tid & 63;
  const int wv   = tid >> 6;        // 0..7
  const int wq   = wv & 3;          // target-group 0..3
  const int grp  = wv >> 2;         // 0 = even chunks, 1 = odd chunks
  const int m    = lane & 31;
  const int g    = lane >> 5;

  const int b  = blockIdx.x >> 4;
  const int t0 = (blockIdx.x & 15) * TTILE;

  // ---- Q fragments fp16 (B-operand: B[k=g*8+j][n=m]) ----
  const int tq = t0 + wq * 32 + m;
  const float* qp = dq + ((size_t)tq * BATCH + b) * HDIM;
  f16x8 qh[16];
#pragma unroll
  for (int kb = 0; kb < 16; ++kb) {
    int h = kb * 16 + g * 8;
    float4 f0 = *(const float4*)(qp + h);
    float4 f1 = *(const float4*)(qp + h + 4);
    float xs[8] = {f0.x, f0.y, f0.z, f0.w, f1.x, f1.y, f1.z, f1.w};
    u16x8 hb;
#pragma unroll
    for (int j = 0; j < 8; ++j)
      hb[j] = __builtin_bit_cast(u16, (_Float16)xs[j]);
    qh[kb] = __builtin_bit_cast(f16x8, hb);
  }

  f32x16 ctx[8];
#pragma unroll
  for (int ht = 0; ht < 8; ++ht) ctx[ht] = (f32x16)(0.0f);
  float dsum = 0.0f;

  // ---- staging: wave wv owns 8 KB of the 64 KB pair-stage ----
  // wv 0,1: KH chunk 2j | wv 2,3: VT 2j | wv 4,5: KH 2j+1 | wv 6,7: VT 2j+1
  const bool isVT  = (wv >> 1) & 1;
  const int  choff = wv >> 2;
  const int  subbase = (wv & 1) * 8;
  const u16* srcArr = isVT ? VT : KH;
  auto stage = [&](int jpair) {
    int ckk = 2 * jpair + choff;
    int buf = ckk & 3;
    size_t tb = ((size_t)b * NCHUNK + ckk) * TILE_U16;
    u16* dst = isVT ? &VTs[buf][0] : &KHs[buf][0];
#pragma unroll
    for (int i = 0; i < 8; ++i) {
      int sub = subbase + i;
      __builtin_amdgcn_global_load_lds(
          (gp1_t)(const void*)&srcArr[tb + (size_t)sub * 512 + lane * 8],
          (lp3_t)(void*)&dst[sub * 512], 16, 0, 0);
    }
  };

  stage(0);

  for (int j = 0; j < 32; ++j) {
    __syncthreads();                 // pair j staged; pair j-1 reads done
    if (j < 31) stage(j + 1);
    const int ckk = 2 * j + grp;     // this wave's chunk
    const int buf = ckk & 3;

    // ---- QK^T as S^T (m=s, n=t), fp16, two independent chains ----
    f32x16 a0 = (f32x16)(0.0f), a1 = (f32x16)(0.0f);
#pragma unroll
    for (int kb = 0; kb < 16; kb += 2) {
      f16x8 k0 = __builtin_bit_cast(f16x8, *(const u16x8*)&KHs[buf][kb * 512 + lane * 8]);
      f16x8 k1 = __builtin_bit_cast(f16x8, *(const u16x8*)&KHs[buf][(kb + 1) * 512 + lane * 8]);
      a0 = __builtin_amdgcn_mfma_f32_32x32x16_f16(k0, qh[kb], a0, 0, 0, 0);
      a1 = __builtin_amdgcn_mfma_f32_32x32x16_f16(k1, qh[kb + 1], a1, 0, 0, 0);
    }

    // ---- exp(s-128), denom; pack bf16 pairs into u32 ----
    // C/D reg r holds s=(r&3)+8*(r>>2)+4g, t=m
    u32 pk[8];
    {
      float l0 = 0.f, l1 = 0.f;
#pragma unroll
      for (int i = 0; i < 8; ++i) {
        float pf0 = __expf(a0[2 * i] + a1[2 * i] - 128.0f);
        float pf1 = __expf(a0[2 * i + 1] + a1[2 * i + 1] - 128.0f);
        l0 += pf0; l1 += pf1;
        pk[i] = (u32)f2bf(pf0) | ((u32)f2bf(pf1) << 16);
      }
      dsum += l0 + l1;
    }

    // ---- C-layout -> A-layout in registers: swap reg-quads across g ----
    // pa0 (s window 0..15):  g=0: {pk0,pk1,pp0,pp1}  g=1: {pp2,pp3,pk2,pk3}
    // pa1 (s window 16..31): g=0: {pk4,pk5,pp4,pp5}  g=1: {pp6,pp7,pk6,pk7}
    u32 pp[8];
#pragma unroll
    for (int i = 0; i < 8; ++i)
      pp[i] = __shfl_xor(pk[i], 32, 64);
    u32x4 w0, w1;
    if (g == 0) {
      w0 = (u32x4){pk[0], pk[1], pp[0], pp[1]};
      w1 = (u32x4){pk[4], pk[5], pp[4], pp[5]};
    } else {
      w0 = (u32x4){pp[2], pp[3], pk[2], pk[3]};
      w1 = (u32x4){pp[6], pp[7], pk[6], pk[7]};
    }
    bf16x8 pa0 = __builtin_bit_cast(bf16x8, w0);
    bf16x8 pa1 = __builtin_bit_cast(bf16x8, w1);

    // ---- PV: ctx(m=t, n=h) += P * V ----
#pragma unroll
    for (int ht = 0; ht < 8; ++ht) {
      bf16x8 v0 = __builtin_bit_cast(bf16x8, *(const u16x8*)&VTs[buf][(ht * 2) * 512 + lane * 8]);
      bf16x8 v1 = __builtin_bit_cast(bf16x8, *(const u16x8*)&VTs[buf][(ht * 2 + 1) * 512 + lane * 8]);
      ctx[ht] = __builtin_amdgcn_mfma_f32_32x32x16_bf16(pa0, v0, ctx[ht], 0, 0, 0);
      ctx[ht] = __builtin_amdgcn_mfma_f32_32x32x16_bf16(pa1, v1, ctx[ht], 0, 0, 0);
    }
  }

  // ---- combine the two source-halves (exact: same exp offset) ----
  dsum += __shfl_xor(dsum, 32, 64);   // per-lane: partial denom for t = m
  __syncthreads();                    // all K-loop LDS reads done; bufs reusable

  float* exch = (wq < 2) ? (float*)&KHs[wq * 2][0] : (float*)&VTs[(wq - 2) * 2][0];

  if (grp == 1) {
#pragma unroll
    for (int r4 = 0; r4 < 4; ++r4)
#pragma unroll
      for (int ht = 0; ht < 8; ++ht) {
        f32x4 v = {ctx[ht][r4 * 4], ctx[ht][r4 * 4 + 1],
                   ctx[ht][r4 * 4 + 2], ctx[ht][r4 * 4 + 3]};
        *(f32x4*)&exch[r4 * 2048 + ht * 256 + lane * 4] = v;
      }
    Ds[wq][lane] = dsum;
  }
  __syncthreads();

  if (grp == 0) {
    float dB = Ds[wq][lane];
    float inv = 1.0f / (dsum + dB);
#pragma unroll
    for (int r4 = 0; r4 < 4; ++r4)
#pragma unroll
      for (int ht = 0; ht < 8; ++ht) {
        f32x4 v = *(const f32x4*)&exch[r4 * 2048 + ht * 256 + lane * 4];
        ctx[ht][r4 * 4]     += v[0];
        ctx[ht][r4 * 4 + 1] += v[1];
        ctx[ht][r4 * 4 + 2] += v[2];
        ctx[ht][r4 * 4 + 3] += v[3];
      }
#pragma unroll
    for (int r = 0; r < 16; ++r) {
      int tl = (r & 3) + 8 * (r >> 2) + 4 * g;
      float rinv = __shfl(inv, tl, 64);
      int t = t0 + wq * 32 + tl;
      float* op = out + ((size_t)t * BATCH + b) * HDIM + m;
#pragma unroll
      for (int ht = 0; ht < 8; ++ht)
        op[ht * 32] = ctx[ht][r] * rinv;
    }
  }
}

extern "C" void kernel_launch(void* const* d_in, const int* in_sizes, int n_in,
                              void* d_out, int out_size, void* d_ws, size_t ws_size,
                              hipStream_t stream) {
  const float* e  = (const float*)d_in[0];  // out_e [2048, 16, 512]
  const float* dq = (const float*)d_in[1];  // out_d [2048, 16, 256]
  float* out = (float*)d_out;               // [2048, 16, 256]
  u16* KH = (u16*)d_ws;                                 // fp16 bits, 16 MB
  u16* VT = KH + (size_t)NTILES * TILE_U16;             // bf16 bits, 16 MB
  prepass_kernel<<<dim3(NTILES), dim3(256), 0, stream>>>(e, KH, VT);
  attn_main_kernel<<<dim3(BATCH * (SEQ / TTILE)), dim3(512), 0, stream>>>(
      KH, VT, dq, out);
}